// Round 5
// baseline (20368.756 us; speedup 1.0000x reference)
//
#include <hip/hip_runtime.h>
#include <hip/hip_fp16.h>
#include <math.h>

// R12: R11 fabric + latency engineering inside the proven transport.
//  R11 post-mortem: sparse MAC halved VALU work but step only went
//  5280->5080 cy => ~4k cy/step is handshake (store visibility + agent-scope
//  poll round + detection quantization + producer skew). This round attacks
//  the quantization and serialization terms, transport unchanged:
//   * 2-deep pipelined polls: two register banks (P,Q), always one round in
//     flight; `s_waitcnt vmcnt(2)` validates the older round while the newer
//     travels. Poll loads are inline-asm global_load_dwordx4 `sc0 sc1` (the
//     PROVEN-visible load form, cf. R8-R10 valve); each lane covers words
//     [tid*8, tid*8+8) as two quads, staged to LDS the round they match.
//   * loop rotation: iteration k issues poll loads for tags k-1 FIRST
//     (no wait), then computes+publishes step k-1 (reads part[] from last
//     iteration), then waits/checks. Publish is never behind a waitcnt.
//     All vmcnt waits are counted so extra older ops (stores) only make the
//     wait stricter - never unsafe.
//   * publish fan-out: lanes tid<128 publish (row=tid>>3, replica=tid&7),
//     one store each (replicas land simultaneously); lanes 128-143 do the
//     out[] store. hcur replicated across the 9 lanes of a row (identical
//     FP ops => bitwise identical).
//  Correctness chain unchanged (R7-proven, shifted by rotation): publish of
//  k-1 precedes own detect of k-1 in-iteration (no withholding => no
//  deadlock); a slot is overwritten (tag k+2 parity) only after every
//  consumer's tag-k read, transitively through the publish->poll dependency.
//  Sparse lists, MAC, reduction, tag scheme: R11 verbatim.

#define NWG        128
#define ROWS_PER_WG 16
#define T_STEPS    8192
#define WARMUP     100
#define RSIZE      2048
#define ISIZE      64
#define OUTCOLS    2112
#define MAXREP     8
#define REP_STRIDE_W 16384    // 64 KB / 4B between replica bases
#define CAPT       24         // sparse entries per lane (R8-proven bound /4)

typedef int i32x4 __attribute__((ext_vector_type(4)));

#define REP24(F) \
  F(0) F(1) F(2) F(3) F(4) F(5) F(6) F(7) \
  F(8) F(9) F(10) F(11) F(12) F(13) F(14) F(15) \
  F(16) F(17) F(18) F(19) F(20) F(21) F(22) F(23)

#define REP12(F) \
  F(0) F(1) F(2) F(3) F(4) F(5) F(6) F(7) F(8) F(9) F(10) F(11)

#define PAIRS12(F) \
  F(0,0,1) F(1,2,3) F(2,4,5) F(3,6,7) F(4,8,9) F(5,10,11) \
  F(6,12,13) F(7,14,15) F(8,16,17) F(9,18,19) F(10,20,21) F(11,22,23)

#define DECLV(I) float v##I = 0.0f;
#define DECLO(I) unsigned op##I = 0u;
#define SETV(I)  v##I = sv[l * CAPT + (I)];
#define SETO(I)  op##I = (unsigned)si[l * CAPT + 2 * (I)] | ((unsigned)si[l * CAPT + 2 * (I) + 1] << 16);
#define PINV(I)  asm volatile("" : "+v"(v##I));
#define PINO(I)  asm volatile("" : "+v"(op##I));
#define MAC2(P, A, B) \
  if ((A) < cm) { f0 = fmaf(v##A, *(const float*)(hsb + (op##P & 0xFFFFu)), f0); } \
  if ((B) < cm) { f1 = fmaf(v##B, *(const float*)(hsb + (op##P >> 16)),     f1); }

static __device__ __forceinline__ float h16_to_f32(unsigned short u) {
    __half_raw hr; hr.x = u;
    return __half2float(__half(hr));
}
static __device__ __forceinline__ unsigned short f32_to_h16(float f) {
    __half_raw hr = __half_raw(__float2half_rn(f));
    return hr.x;
}

__global__ __launch_bounds__(256) void init_ws_kernel(unsigned* rep0, int nrep) {
    int t = blockIdx.x * blockDim.x + threadIdx.x;
    if (t < nrep * RSIZE) {
        int rep = t >> 11;          // RSIZE = 2048
        int idx = t & (RSIZE - 1);
        unsigned* b = rep0 + rep * REP_STRIDE_W;
        b[idx]         = 0u;           // buf0: (tag=0, h_0 = fp16 0)
        b[RSIZE + idx] = 0xFFFF0000u;  // buf1: tag 0xFFFF never matches
    }
}

__global__ __launch_bounds__(256) void xcopy_kernel(const float* __restrict__ x,
                                                    float* __restrict__ out) {
    int t = blockIdx.x * blockDim.x + threadIdx.x;
    if (t >= (T_STEPS - WARMUP) * ISIZE) return;
    int rowo = t >> 6;          // output row 0..8091
    int j    = t & 63;
    out[(size_t)rowo * OUTCOLS + RSIZE + j] = x[(size_t)(rowo + WARMUP) * ISIZE + j];
}

__global__ __launch_bounds__(256, 1) void esn_scan_kernel(
    const float* __restrict__ x,    // [8192][64]
    const float* __restrict__ Win,  // [2048][64]
    const float* __restrict__ Wh,   // [2048][2048]
    float* __restrict__ out,        // [8092][2112]
    unsigned* rep0,                 // replica 0 base; replicas at +r*REP_STRIDE_W
    int nrep, int repmask)          // nrep = pow2 in [1,8], repmask = nrep-1
{
    __shared__ __align__(16) float hs[RSIZE];     // staged h (word i at hs[i])
    __shared__ float part[64];                    // part[row*4 + w]
    __shared__ float sv[64 * CAPT];               // build scratch (per-wave phases)
    __shared__ unsigned short si[64 * CAPT];

    const int tid = threadIdx.x;      // 0..255
    const int wg  = blockIdx.x;       // 0..127
    const int w   = tid >> 6;         // wave 0..3 -> segment [512w, 512w+512)
    const int l   = tid & 63;         // lane
    const int r4  = l >> 2;           // row within WG served by this lane, 0..15
    const int c4  = l & 3;            // parity class of compacted nonzeros, 0..3
    const int row = wg * ROWS_PER_WG + r4;
    const int seg = w * 512;
    const char* hsb = (const char*)hs;

    // My poll replica (fixed per WG)
    const unsigned* myrep = rep0 + (wg & repmask) * REP_STRIDE_W;

    // ---- build sparse (val, byteoff) register lists, wave-staggered (R11) ----
    int cnt = 0;
    REP24(DECLV)
    REP12(DECLO)
    const float* wrow = Wh + (size_t)row * RSIZE + seg;
    for (int ph = 0; ph < 4; ++ph) {
        if (w == ph) {
            for (int i = 0; i < CAPT; ++i) { sv[l * CAPT + i] = 0.0f; si[l * CAPT + i] = 0; }
            int c = 0, c2 = 0;
            #pragma unroll 8
            for (int j = 0; j < 512; j += 4) {
                const float4 t4 = *(const float4*)(wrow + j);
                #define TAKE(VAL, COMP) \
                    if ((VAL) != 0.0f) { \
                        if ((c & 3) == c4 && c2 < CAPT) { \
                            sv[l * CAPT + c2] = (VAL); \
                            si[l * CAPT + c2] = (unsigned short)((seg + j + (COMP)) * 4); \
                            ++c2; \
                        } \
                        ++c; \
                    }
                TAKE(t4.x, 0) TAKE(t4.y, 1) TAKE(t4.z, 2) TAKE(t4.w, 3)
                #undef TAKE
            }
            cnt = c2;
            REP24(SETV)
            REP12(SETO)
        }
        __syncthreads();
    }
    REP24(PINV)
    REP12(PINO)

    // wave-uniform trip count (zero-padded entries are benign)
    int cm = cnt;
    #pragma unroll
    for (int d = 1; d < 64; d <<= 1) { const int o = __shfl_xor(cm, d); cm = o > cm ? o : cm; }
    cm = __builtin_amdgcn_readfirstlane(cm);

    // pinned Win chunk: row, x-cols [16w + 4*c4, +4)
    float wix, wiy, wiz, wiw;
    { float4 t = *(const float4*)(Win + (size_t)row * ISIZE + w * 16 + c4 * 4);
      wix = t.x; wiy = t.y; wiz = t.z; wiw = t.w; }
    asm volatile("" : "+v"(wix), "+v"(wiy), "+v"(wiz), "+v"(wiw));

    // publish roles: tid<128 -> (row tid>>3, replica tid&7); 128..143 -> out row tid-128
    const int prow = (tid < 128) ? (tid >> 3) : (tid - 128);
    float hcur = 0.0f;  // tracked by tid<144 (replicated per row; identical ops)

    i32x4 xi, pA, pB, qA, qB;

    for (int k = 1; k <= T_STEPS; ++k) {
        const int psel = ((k - 1) & 1) ? RSIZE : 0;
        const unsigned* pb = myrep + psel + tid * 8;
        const float* xp = x + (size_t)(k - 1) * ISIZE + w * 16 + c4 * 4;

        // ---- 1. issue x + both poll banks (no wait) ----
        asm volatile(
            "global_load_dwordx4 %0, %5, off\n\t"
            "global_load_dwordx4 %1, %6, off sc0 sc1\n\t"
            "global_load_dwordx4 %2, %6, off offset:16 sc0 sc1\n\t"
            "global_load_dwordx4 %3, %6, off sc0 sc1\n\t"
            "global_load_dwordx4 %4, %6, off offset:16 sc0 sc1\n\t"
            : "=&v"(xi), "=&v"(pA), "=&v"(pB), "=&v"(qA), "=&v"(qB)
            : "v"(xp), "v"(pb)
            : "memory");

        // ---- 2. publish step k-1 (value from part[] written last iteration) ----
        if (k > 1 && tid < 144) {
            const float4 ps = *(const float4*)(part + prow * 4);
            float y = ps.x + ps.y + ps.z + ps.w;
            float ax = fabsf(y);
            float e  = __expf(2.0f * ax);
            float t  = 1.0f - 2.0f / (e + 1.0f);
            t = copysignf(t, y);
            hcur = 0.99f * hcur + 0.01f * t;
            if (tid < 128) {
                if ((tid & 7) < nrep) {
                    const unsigned word = ((unsigned)(k - 1) << 16) | (unsigned)f32_to_h16(hcur);
                    const int slot = psel + wg * ROWS_PER_WG + prow;
                    __hip_atomic_store(rep0 + (tid & 7) * REP_STRIDE_W + slot, word,
                                       __ATOMIC_RELAXED, __HIP_MEMORY_SCOPE_AGENT);
                }
            } else if (k - 1 >= WARMUP + 1) {
                __builtin_nontemporal_store(
                    hcur, out + (size_t)(k - 1 - (WARMUP + 1)) * OUTCOLS + wg * ROWS_PER_WG + prow);
            }
        }

        // ---- 3. wait: x + bank P valid (bank Q still in flight) ----
        asm volatile("s_waitcnt vmcnt(2)"
                     : "+v"(xi), "+v"(pA), "+v"(pB) :: "memory");

        // ---- 4. check/stage loop, 2-deep pipelined ----
        const unsigned expw = (unsigned)(k - 1) << 16;
        unsigned dmask = 3u;

        #define CHECK_STAGE(QA, QB) do { \
            if (dmask & 1u) { \
                const unsigned d0 = (((unsigned)(QA).x ^ expw) | ((unsigned)(QA).y ^ expw) | \
                                     ((unsigned)(QA).z ^ expw) | ((unsigned)(QA).w ^ expw)) & 0xFFFF0000u; \
                if (d0 == 0u) { \
                    float4 f; \
                    f.x = h16_to_f32((unsigned short)((QA).x & 0xFFFF)); \
                    f.y = h16_to_f32((unsigned short)((QA).y & 0xFFFF)); \
                    f.z = h16_to_f32((unsigned short)((QA).z & 0xFFFF)); \
                    f.w = h16_to_f32((unsigned short)((QA).w & 0xFFFF)); \
                    *(float4*)(hs + tid * 8) = f; \
                    dmask &= ~1u; \
                } \
            } \
            if (dmask & 2u) { \
                const unsigned d1 = (((unsigned)(QB).x ^ expw) | ((unsigned)(QB).y ^ expw) | \
                                     ((unsigned)(QB).z ^ expw) | ((unsigned)(QB).w ^ expw)) & 0xFFFF0000u; \
                if (d1 == 0u) { \
                    float4 f; \
                    f.x = h16_to_f32((unsigned short)((QB).x & 0xFFFF)); \
                    f.y = h16_to_f32((unsigned short)((QB).y & 0xFFFF)); \
                    f.z = h16_to_f32((unsigned short)((QB).z & 0xFFFF)); \
                    f.w = h16_to_f32((unsigned short)((QB).w & 0xFFFF)); \
                    *(float4*)(hs + tid * 8 + 4) = f; \
                    dmask &= ~2u; \
                } \
            } \
        } while (0)

        #define POLL_ROUND(NA, NB, OA, OB) \
            asm volatile("global_load_dwordx4 %0, %4, off sc0 sc1\n\t" \
                         "global_load_dwordx4 %1, %4, off offset:16 sc0 sc1\n\t" \
                         "s_waitcnt vmcnt(2)" \
                         : "=&v"(NA), "=&v"(NB), "+v"(OA), "+v"(OB) \
                         : "v"(pb) : "memory")

        CHECK_STAGE(pA, pB);
        while (dmask) {
            POLL_ROUND(pA, pB, qA, qB);   // reissue P; validate Q
            CHECK_STAGE(qA, qB);
            if (!dmask) break;
            POLL_ROUND(qA, qB, pA, pB);   // reissue Q; validate P
            CHECK_STAGE(pA, pB);
        }
        #undef POLL_ROUND
        #undef CHECK_STAGE

        // ---- 5. Win.x partial + sparse MAC (same-wave ds ordering) ----
        float f0 = wix * __int_as_float(xi.x);
        f0 = fmaf(wiy, __int_as_float(xi.y), f0);
        f0 = fmaf(wiz, __int_as_float(xi.z), f0);
        f0 = fmaf(wiw, __int_as_float(xi.w), f0);
        float f1 = 0.0f;

        PAIRS12(MAC2)

        // reduce over the 4 c4 lanes
        float p = f0 + f1;
        p += __shfl_xor(p, 1);
        p += __shfl_xor(p, 2);
        if (c4 == 0) part[r4 * 4 + w] = p;

        // ---- 6. drain stale in-flight polls before bank reuse; barrier ----
        asm volatile("s_waitcnt vmcnt(0)" ::: "memory");
        __syncthreads();   // the ONE barrier: guards part[] write -> next-iter read
    }

    // ---- epilogue: publish step T_STEPS's output row (out only) ----
    if (tid >= 128 && tid < 144) {
        const float4 ps = *(const float4*)(part + prow * 4);
        float y = ps.x + ps.y + ps.z + ps.w;
        float ax = fabsf(y);
        float e  = __expf(2.0f * ax);
        float t  = 1.0f - 2.0f / (e + 1.0f);
        t = copysignf(t, y);
        hcur = 0.99f * hcur + 0.01f * t;
        __builtin_nontemporal_store(
            hcur, out + (size_t)(T_STEPS - (WARMUP + 1)) * OUTCOLS + wg * ROWS_PER_WG + prow);
    }
}

extern "C" void kernel_launch(void* const* d_in, const int* in_sizes, int n_in,
                              void* d_out, int out_size, void* d_ws, size_t ws_size,
                              hipStream_t stream) {
    const float* x   = (const float*)d_in[0];  // [8192*64]
    const float* Win = (const float*)d_in[1];  // [2048*64]
    const float* Wh  = (const float*)d_in[2];  // [2048*2048]
    float* out = (float*)d_out;                // [8092*2112]

    unsigned* rep0 = (unsigned*)d_ws;

    // nrep = largest power of two <= min(8, ws_size / 64KB)
    int nrep = MAXREP;
    while (nrep > 1 && (size_t)nrep * (REP_STRIDE_W * 4) > ws_size) nrep >>= 1;
    int repmask = nrep - 1;

    // init all replicas (ws is poisoned before every timed launch)
    {
        int n = nrep * RSIZE;
        init_ws_kernel<<<(n + 255) / 256, 256, 0, stream>>>(rep0, nrep);
    }

    // x-part of the output, independent of the recurrence
    {
        int n = (T_STEPS - WARMUP) * ISIZE;
        xcopy_kernel<<<(n + 255) / 256, 256, 0, stream>>>(x, out);
    }

    // the sequential scan: 128 persistent workgroups
    esn_scan_kernel<<<NWG, 256, 0, stream>>>(x, Win, Wh, out, rep0, nrep, repmask);
}

// Round 6
// 19064.066 us; speedup vs baseline: 1.0684x; 1.0684x over previous
//
#include <hip/hip_runtime.h>
#include <hip/hip_fp16.h>
#include <math.h>

// R13: R11 fabric + streaming-cadence poll + publish fan-out.
//  R12 post-mortem: regression came from (a) end-of-step vmcnt(0) draining
//  JUST-issued loads (~700cy/step), (b) 2x poll reissue traffic, (c) staging
//  layout with 4-bank aliasing. The counted-wait idea itself was sound.
//  This round, minimal deltas on R11 (17.36ms):
//   * streaming poll: 4 b64 slots per lane kept permanently in flight;
//     `s_waitcnt vmcnt(3)` validates only the OLDEST slot, check, reissue
//     that slot. Checks fire every ~175cy instead of every ~700cy round
//     (same steady traffic rate: 4 loads per ~700cy per lane). Detection
//     quantization - which the 128-WG max-tail amplifies to ~700cy/step -
//     drops ~4x. Matched slots stage to LDS immediately (R11 layout, 2l
//     word pattern = free 2-way banking).
//   * the residual vmcnt(0) sits AFTER the MAC/reduce phase: stale slots
//     aged >= 175cy + ~600cy of MAC => drain cost ~0 (R12's mistake fixed).
//   * x load folded into the poll asm stream (vmcnt(4) consumes it) so the
//     compiler never inserts its own draining wait mid-pipeline.
//   * publish fan-out: lanes tid<128 store (row=tid>>3, replica=tid&7), one
//     agent store each; lanes 128-143 write out[]. hcur replicated per row
//     (identical FP ops => bitwise identical). R11 loop position (publish at
//     END of iteration k, after the single barrier) - no rotation.
//  Counted-wait safety: publish/out stores are OLDER than poll loads in
//  program order; extra older ops only make vmcnt(N) stricter. Wave-level
//  vmcnt counts instructions, so lane divergence in the check is benign.
//  Correctness chain (R7-proven): publish of tag k precedes any WG's detect
//  of k; slot overwrite (tag k+2) gated transitively through every
//  consumer's tag-k read. Sparse lists / MAC / reduction: R11 verbatim.

#define NWG        128
#define ROWS_PER_WG 16
#define T_STEPS    8192
#define WARMUP     100
#define RSIZE      2048
#define ISIZE      64
#define OUTCOLS    2112
#define MAXREP     8
#define REP_STRIDE_W 16384    // 64 KB / 4B between replica bases
#define CAPT       24         // sparse entries per lane (R8-proven bound /4)

typedef int i32x4 __attribute__((ext_vector_type(4)));
typedef int i32x2 __attribute__((ext_vector_type(2)));

#define REP24(F) \
  F(0) F(1) F(2) F(3) F(4) F(5) F(6) F(7) \
  F(8) F(9) F(10) F(11) F(12) F(13) F(14) F(15) \
  F(16) F(17) F(18) F(19) F(20) F(21) F(22) F(23)

#define REP12(F) \
  F(0) F(1) F(2) F(3) F(4) F(5) F(6) F(7) F(8) F(9) F(10) F(11)

#define PAIRS12(F) \
  F(0,0,1) F(1,2,3) F(2,4,5) F(3,6,7) F(4,8,9) F(5,10,11) \
  F(6,12,13) F(7,14,15) F(8,16,17) F(9,18,19) F(10,20,21) F(11,22,23)

#define DECLV(I) float v##I = 0.0f;
#define DECLO(I) unsigned op##I = 0u;
#define SETV(I)  v##I = sv[l * CAPT + (I)];
#define SETO(I)  op##I = (unsigned)si[l * CAPT + 2 * (I)] | ((unsigned)si[l * CAPT + 2 * (I) + 1] << 16);
#define PINV(I)  asm volatile("" : "+v"(v##I));
#define PINO(I)  asm volatile("" : "+v"(op##I));
#define MAC2(P, A, B) \
  if ((A) < cm) { f0 = fmaf(v##A, *(const float*)(hsb + (op##P & 0xFFFFu)), f0); } \
  if ((B) < cm) { f1 = fmaf(v##B, *(const float*)(hsb + (op##P >> 16)),     f1); }

static __device__ __forceinline__ float h16_to_f32(unsigned short u) {
    __half_raw hr; hr.x = u;
    return __half2float(__half(hr));
}
static __device__ __forceinline__ unsigned short f32_to_h16(float f) {
    __half_raw hr = __half_raw(__float2half_rn(f));
    return hr.x;
}

__global__ __launch_bounds__(256) void init_ws_kernel(unsigned* rep0, int nrep) {
    int t = blockIdx.x * blockDim.x + threadIdx.x;
    if (t < nrep * RSIZE) {
        int rep = t >> 11;          // RSIZE = 2048
        int idx = t & (RSIZE - 1);
        unsigned* b = rep0 + rep * REP_STRIDE_W;
        b[idx]         = 0u;           // buf0: (tag=0, h_0 = fp16 0)
        b[RSIZE + idx] = 0xFFFF0000u;  // buf1: tag 0xFFFF never matches
    }
}

__global__ __launch_bounds__(256) void xcopy_kernel(const float* __restrict__ x,
                                                    float* __restrict__ out) {
    int t = blockIdx.x * blockDim.x + threadIdx.x;
    if (t >= (T_STEPS - WARMUP) * ISIZE) return;
    int rowo = t >> 6;          // output row 0..8091
    int j    = t & 63;
    out[(size_t)rowo * OUTCOLS + RSIZE + j] = x[(size_t)(rowo + WARMUP) * ISIZE + j];
}

__global__ __launch_bounds__(256, 1) void esn_scan_kernel(
    const float* __restrict__ x,    // [8192][64]
    const float* __restrict__ Win,  // [2048][64]
    const float* __restrict__ Wh,   // [2048][2048]
    float* __restrict__ out,        // [8092][2112]
    unsigned* rep0,                 // replica 0 base; replicas at +r*REP_STRIDE_W
    int nrep, int repmask)          // nrep = pow2 in [1,8], repmask = nrep-1
{
    __shared__ __align__(16) float hs[RSIZE];     // staged h (word i at hs[i])
    __shared__ __align__(16) float part[64];      // part[row*4 + w]
    __shared__ float sv[64 * CAPT];               // build scratch (per-wave phases)
    __shared__ unsigned short si[64 * CAPT];

    const int tid = threadIdx.x;      // 0..255
    const int wg  = blockIdx.x;       // 0..127
    const int w   = tid >> 6;         // wave 0..3 -> segment [512w, 512w+512)
    const int l   = tid & 63;         // lane
    const int r4  = l >> 2;           // row within WG served by this lane, 0..15
    const int c4  = l & 3;            // parity class of compacted nonzeros, 0..3
    const int row = wg * ROWS_PER_WG + r4;
    const int seg = w * 512;
    const char* hsb = (const char*)hs;

    // My poll replica (fixed per WG)
    const unsigned* myrep = rep0 + (wg & repmask) * REP_STRIDE_W;

    // ---- build sparse (val, byteoff) register lists, wave-staggered (R11) ----
    int cnt = 0;
    REP24(DECLV)
    REP12(DECLO)
    const float* wrow = Wh + (size_t)row * RSIZE + seg;
    for (int ph = 0; ph < 4; ++ph) {
        if (w == ph) {
            for (int i = 0; i < CAPT; ++i) { sv[l * CAPT + i] = 0.0f; si[l * CAPT + i] = 0; }
            int c = 0, c2 = 0;
            #pragma unroll 8
            for (int j = 0; j < 512; j += 4) {
                const float4 t4 = *(const float4*)(wrow + j);
                #define TAKE(VAL, COMP) \
                    if ((VAL) != 0.0f) { \
                        if ((c & 3) == c4 && c2 < CAPT) { \
                            sv[l * CAPT + c2] = (VAL); \
                            si[l * CAPT + c2] = (unsigned short)((seg + j + (COMP)) * 4); \
                            ++c2; \
                        } \
                        ++c; \
                    }
                TAKE(t4.x, 0) TAKE(t4.y, 1) TAKE(t4.z, 2) TAKE(t4.w, 3)
                #undef TAKE
            }
            cnt = c2;
            REP24(SETV)
            REP12(SETO)
        }
        __syncthreads();
    }
    REP24(PINV)
    REP12(PINO)

    // wave-uniform trip count (zero-padded entries are benign)
    int cm = cnt;
    #pragma unroll
    for (int d = 1; d < 64; d <<= 1) { const int o = __shfl_xor(cm, d); cm = o > cm ? o : cm; }
    cm = __builtin_amdgcn_readfirstlane(cm);

    // pinned Win chunk: row, x-cols [16w + 4*c4, +4)
    float wix, wiy, wiz, wiw;
    { float4 t = *(const float4*)(Win + (size_t)row * ISIZE + w * 16 + c4 * 4);
      wix = t.x; wiy = t.y; wiz = t.z; wiw = t.w; }
    asm volatile("" : "+v"(wix), "+v"(wiy), "+v"(wiz), "+v"(wiw));

    // publish roles: tid<128 -> (row tid>>3, replica tid&7); 128..143 -> out row tid-128
    const int prow = (tid < 128) ? (tid >> 3) : (tid - 128);
    float hcur = 0.0f;  // tracked by tid<144 (replicated per row; identical ops)

    i32x4 xi;
    i32x2 q0, q1, q2, q3;

    for (int k = 1; k <= T_STEPS; ++k) {
        const int psel = ((k - 1) & 1) ? RSIZE : 0;
        const unsigned* lp = myrep + psel + seg + 2 * l;   // slots at +s*128 words
        const float* xp = x + (size_t)(k - 1) * ISIZE + w * 16 + c4 * 4;

        // ---- issue x + all 4 poll slots (oldest-first: x, q0, q1, q2, q3) ----
        asm volatile(
            "global_load_dwordx4 %0, %5, off\n\t"
            "global_load_dwordx2 %1, %6, off sc0 sc1\n\t"
            "global_load_dwordx2 %2, %6, off offset:512 sc0 sc1\n\t"
            "global_load_dwordx2 %3, %6, off offset:1024 sc0 sc1\n\t"
            "global_load_dwordx2 %4, %6, off offset:1536 sc0 sc1\n\t"
            : "=&v"(xi), "=&v"(q0), "=&v"(q1), "=&v"(q2), "=&v"(q3)
            : "v"(xp), "v"(lp)
            : "memory");

        // ---- consume x (vmcnt(4): x + any older stores retired) ----
        asm volatile("s_waitcnt vmcnt(4)" : "+v"(xi) :: "memory");
        float f0 = wix * __int_as_float(xi.x);
        f0 = fmaf(wiy, __int_as_float(xi.y), f0);
        f0 = fmaf(wiz, __int_as_float(xi.z), f0);
        f0 = fmaf(wiw, __int_as_float(xi.w), f0);
        float f1 = 0.0f;

        // ---- streaming cadence poll: validate oldest slot, check, reissue ----
        const unsigned expw = (unsigned)(k - 1) << 16;
        unsigned m = 0xFu;

        #define SLOT(S, Q, OFFSTR) \
            asm volatile("s_waitcnt vmcnt(3)" : "+v"(Q) :: "memory"); \
            if (m & (1u << (S))) { \
                const unsigned a_ = (unsigned)(Q).x, b_ = (unsigned)(Q).y; \
                if ((((a_ ^ expw) | (b_ ^ expw)) & 0xFFFF0000u) == 0u) { \
                    float2 v_; \
                    v_.x = h16_to_f32((unsigned short)(a_ & 0xFFFFu)); \
                    v_.y = h16_to_f32((unsigned short)(b_ & 0xFFFFu)); \
                    *(float2*)(hs + seg + (S) * 128 + 2 * l) = v_; \
                    m &= ~(1u << (S)); \
                    if (!m) break; \
                } \
            } \
            asm volatile("global_load_dwordx2 %0, %1, off " OFFSTR " sc0 sc1" \
                         : "=&v"(Q) : "v"(lp) : "memory");

        for (;;) {
            SLOT(0, q0, "")
            SLOT(1, q1, "offset:512")
            SLOT(2, q2, "offset:1024")
            SLOT(3, q3, "offset:1536")
        }
        #undef SLOT

        // ---- sparse MAC over my row's parity-class entries (same-wave ds) ----
        PAIRS12(MAC2)

        // reduce over the 4 c4 lanes
        float p = f0 + f1;
        p += __shfl_xor(p, 1);
        p += __shfl_xor(p, 2);
        if (c4 == 0) part[r4 * 4 + w] = p;

        // stale reissues aged by the whole MAC phase -> this drain is ~free
        asm volatile("s_waitcnt vmcnt(0)" ::: "memory");
        __syncthreads();   // the ONE barrier: guards the 64-float reduction

        // ---- fan-out publish: 128 lanes x 1 store; lanes 128-143 out[] ----
        if (tid < 144) {
            const float4 ps = *(const float4*)(part + prow * 4);
            float y = ps.x + ps.y + ps.z + ps.w;
            float ax = fabsf(y);
            float e  = __expf(2.0f * ax);
            float t  = 1.0f - 2.0f / (e + 1.0f);
            t = copysignf(t, y);
            hcur = 0.99f * hcur + 0.01f * t;
            if (tid < 128) {
                if ((tid & 7) < nrep) {
                    const unsigned word = ((unsigned)k << 16) | (unsigned)f32_to_h16(hcur);
                    const int slot = ((k & 1) ? RSIZE : 0) + wg * ROWS_PER_WG + prow;
                    __hip_atomic_store(rep0 + (tid & 7) * REP_STRIDE_W + slot, word,
                                       __ATOMIC_RELAXED, __HIP_MEMORY_SCOPE_AGENT);
                }
            } else if (k >= WARMUP + 1) {
                __builtin_nontemporal_store(
                    hcur, out + (size_t)(k - (WARMUP + 1)) * OUTCOLS + wg * ROWS_PER_WG + prow);
            }
        }
        // no second barrier: part[] reuse protected by the publish->poll
        // dependency chain + timing asymmetry (R7-proven; publish lanes read
        // part[] immediately post-barrier, any re-writer first needs a full
        // detection+MAC phase).
    }
}

extern "C" void kernel_launch(void* const* d_in, const int* in_sizes, int n_in,
                              void* d_out, int out_size, void* d_ws, size_t ws_size,
                              hipStream_t stream) {
    const float* x   = (const float*)d_in[0];  // [8192*64]
    const float* Win = (const float*)d_in[1];  // [2048*64]
    const float* Wh  = (const float*)d_in[2];  // [2048*2048]
    float* out = (float*)d_out;                // [8092*2112]

    unsigned* rep0 = (unsigned*)d_ws;

    // nrep = largest power of two <= min(8, ws_size / 64KB)
    int nrep = MAXREP;
    while (nrep > 1 && (size_t)nrep * (REP_STRIDE_W * 4) > ws_size) nrep >>= 1;
    int repmask = nrep - 1;

    // init all replicas (ws is poisoned before every timed launch)
    {
        int n = nrep * RSIZE;
        init_ws_kernel<<<(n + 255) / 256, 256, 0, stream>>>(rep0, nrep);
    }

    // x-part of the output, independent of the recurrence
    {
        int n = (T_STEPS - WARMUP) * ISIZE;
        xcopy_kernel<<<(n + 255) / 256, 256, 0, stream>>>(x, out);
    }

    // the sequential scan: 128 persistent workgroups
    esn_scan_kernel<<<NWG, 256, 0, stream>>>(x, Win, Wh, out, rep0, nrep, repmask);
}